// Round 9
// baseline (24.967 us; speedup 1.0000x reference)
//
#include <hip/hip_runtime.h>
#include <math.h>

// RBF layer: out[b,u] = exp(-gamma*||x_b - c_u||^2), B=8192, U=2048, DIM=32, f32.
//
// out = exp2(kg*||x||^2 + kg*||c||^2 + m2*(x.c)); x.c via bf16 hi/lo split
// (3x mfma_f32_16x16x32_bf16, K=32=DIM). Norms full f32. Verified R4-R7.
//
// R8: exact R6 kernel (best known, 21.4us), single lever: nontemporal
// stores ('nt' flag) so the 67MB streaming output bypasses L2 write-allocate
// (8.4MB output/XCD vs 4MB L2 = pure thrash; output is never re-read).
// R8 compile fix: __builtin_nontemporal_store needs a clang ext_vector
// pointer (f32x4), not HIP_vector_type (float4).

#define BATCH   8192
#define UNITS   2048
#define DIM     32
#define BM      64
#define BN      128
#define THREADS 256
#define GRIDY   32
#define ITERS   4      // GRIDY * ITERS * BM == BATCH

typedef __attribute__((ext_vector_type(8))) short s16x8;   // 8 bf16
typedef __attribute__((ext_vector_type(4))) float f32x4;

static __device__ __forceinline__ unsigned bf16_rne(float v) {
    unsigned u = __builtin_bit_cast(unsigned, v);
    return (u + 0x7FFFu + ((u >> 16) & 1u)) >> 16;   // round-to-nearest-even
}

static __device__ __forceinline__ void load8(const float* __restrict__ p, float* v) {
    float4 t0 = *reinterpret_cast<const float4*>(p);
    float4 t1 = *reinterpret_cast<const float4*>(p + 4);
    v[0] = t0.x; v[1] = t0.y; v[2] = t0.z; v[3] = t0.w;
    v[4] = t1.x; v[5] = t1.y; v[6] = t1.z; v[7] = t1.w;
}

static __device__ __forceinline__ void split8(const float* v, s16x8& hi, s16x8& lo) {
#pragma unroll
    for (int j = 0; j < 8; ++j) {
        unsigned h = bf16_rne(v[j]);
        float hf = __builtin_bit_cast(float, h << 16);
        unsigned l = bf16_rne(v[j] - hf);
        hi[j] = (short)h;
        lo[j] = (short)l;
    }
}

__global__ __launch_bounds__(THREADS) void rbf_stream(
    const float* __restrict__ x,
    const float* __restrict__ centers,
    const float* __restrict__ gamma,
    float* __restrict__ out)
{
    const int tid  = threadIdx.x;
    const int wid  = tid >> 6;
    const int lane = tid & 63;
    const int wm   = wid >> 1;        // wave M index 0..1 (32 rows each)
    const int wn   = wid & 1;         // wave N index 0..1 (64 cols each)
    const int l16  = lane & 15;
    const int kq   = lane >> 4;       // 0..3

    const float kg = -gamma[0] * 1.4426950408889634f;  // -g*log2(e)
    const float m2 = -2.0f * kg;

    const int c0 = blockIdx.x * BN;

    // ---- prologue (once per block): center fragments + kg*||c||^2 ----
    s16x8 b_hi[4], b_lo[4];
    float kgcnq[4][4];                // [n][j]: kg*||c_{n*16+kq*4+j}||^2
#pragma unroll
    for (int n = 0; n < 4; ++n) {
        float v[8];
        load8(centers + (size_t)(c0 + wn * 64 + n * 16 + l16) * DIM + kq * 8, v);
        split8(v, b_hi[n], b_lo[n]);
        float pn = 0.f;
#pragma unroll
        for (int j = 0; j < 8; ++j) pn = fmaf(v[j], v[j], pn);
        pn += __shfl_xor(pn, 16);
        pn += __shfl_xor(pn, 32);     // lane now holds ||c_{l16}||^2 of tile n
#pragma unroll
        for (int j = 0; j < 4; ++j)
            kgcnq[n][j] = kg * __shfl(pn, kq * 4 + j);
    }

    // ---- row-tile loop, software-pipelined x loads ----
    float xf[2][2][8];                // [buf][m][elem]
    {
        const int r0 = blockIdx.y * BM;
#pragma unroll
        for (int m = 0; m < 2; ++m)
            load8(x + (size_t)(r0 + wm * 32 + m * 16 + l16) * DIM + kq * 8, xf[0][m]);
    }

#pragma unroll
    for (int k = 0; k < ITERS; ++k) {
        const int cur = k & 1;
        const int r0  = (blockIdx.y + k * GRIDY) * BM;

        if (k + 1 < ITERS) {          // prefetch next tile into other buffer
            const int r1 = (blockIdx.y + (k + 1) * GRIDY) * BM;
#pragma unroll
            for (int m = 0; m < 2; ++m)
                load8(x + (size_t)(r1 + wm * 32 + m * 16 + l16) * DIM + kq * 8,
                      xf[cur ^ 1][m]);
        }

        // convert + per-row norms (wave-local, no LDS)
        s16x8 a_hi[2], a_lo[2];
        float kgxn[2];
#pragma unroll
        for (int m = 0; m < 2; ++m) {
            split8(xf[cur][m], a_hi[m], a_lo[m]);
            float pn = 0.f;
#pragma unroll
            for (int j = 0; j < 8; ++j) pn = fmaf(xf[cur][m][j], xf[cur][m][j], pn);
            pn += __shfl_xor(pn, 16);
            pn += __shfl_xor(pn, 32); // full norm of row l16 (tile m)
            kgxn[m] = kg * pn;
        }

        // MFMA (swapped: D = c . x^T) + epilogue, nontemporal dwordx4 stores
#pragma unroll
        for (int m = 0; m < 2; ++m) {
#pragma unroll
            for (int n = 0; n < 4; ++n) {
                f32x4 acc = {0.f, 0.f, 0.f, 0.f};
                acc = __builtin_amdgcn_mfma_f32_16x16x32_bf16(b_lo[n], a_hi[m], acc, 0, 0, 0);
                acc = __builtin_amdgcn_mfma_f32_16x16x32_bf16(b_hi[n], a_lo[m], acc, 0, 0, 0);
                acc = __builtin_amdgcn_mfma_f32_16x16x32_bf16(b_hi[n], a_hi[m], acc, 0, 0, 0);

                f32x4 o;
                o[0] = __builtin_amdgcn_exp2f(fmaf(m2, acc[0], kgxn[m] + kgcnq[n][0]));
                o[1] = __builtin_amdgcn_exp2f(fmaf(m2, acc[1], kgxn[m] + kgcnq[n][1]));
                o[2] = __builtin_amdgcn_exp2f(fmaf(m2, acc[2], kgxn[m] + kgcnq[n][2]));
                o[3] = __builtin_amdgcn_exp2f(fmaf(m2, acc[3], kgxn[m] + kgcnq[n][3]));

                float* op = out + (size_t)(r0 + wm * 32 + m * 16 + l16) * UNITS
                                + (c0 + wn * 64 + n * 16 + kq * 4);
                __builtin_nontemporal_store(o, reinterpret_cast<f32x4*>(op));
            }
        }
    }
}

extern "C" void kernel_launch(void* const* d_in, const int* in_sizes, int n_in,
                              void* d_out, int out_size, void* d_ws, size_t ws_size,
                              hipStream_t stream)
{
    const float* x       = (const float*)d_in[0];
    const float* centers = (const float*)d_in[1];
    const float* gamma   = (const float*)d_in[2];
    float* out           = (float*)d_out;

    dim3 grid(UNITS / BN, GRIDY);     // (16, 32) = 512 blocks
    dim3 block(THREADS);
    rbf_stream<<<grid, block, 0, stream>>>(x, centers, gamma, out);
}

// Round 10
// 20.394 us; speedup vs baseline: 1.2243x; 1.2243x over previous
//
#include <hip/hip_runtime.h>
#include <math.h>

// RBF layer: out[b,u] = exp(-gamma*||x_b - c_u||^2), B=8192, U=2048, DIM=32, f32.
//
// out = exp2(kg*||x||^2 + kg*||c||^2 + m2*(x.c)); x.c via bf16 hi/lo split
// (3x mfma_f32_16x16x32_bf16, K=32=DIM). Norms full f32. Verified R4-R9.
//
// R9 post-mortem: nt stores REFUTED (write amplification 65.5->83.4 MB: L2
// write-combining of our 64B segments is beneficial). Reverted.
// R10 theory: the 2x write-BW gap vs fills is HBM page locality of the L2
// EVICTION stream. Fix: XCD-slab mapping. xcd = bid&7 (round-robin dispatch);
// each XCD owns a contiguous 1024-row slab; its 64 blocks (16 col x 4 slot)
// walk row-blocks so each k-step writes one contiguous 2MB window per XCD
// -> dirty lines cluster -> evictions approximate a linear sweep.
// Kernel body otherwise identical to R6 (best known, 21.4us).

#define BATCH   8192
#define UNITS   2048
#define DIM     32
#define BM      64
#define BN      128
#define THREADS 256
#define NXCD    8
#define ITERS   4      // 8 xcd * 4 slot * 4 iter * 64 rows = 8192

typedef __attribute__((ext_vector_type(8))) short s16x8;   // 8 bf16
typedef __attribute__((ext_vector_type(4))) float f32x4;

static __device__ __forceinline__ unsigned bf16_rne(float v) {
    unsigned u = __builtin_bit_cast(unsigned, v);
    return (u + 0x7FFFu + ((u >> 16) & 1u)) >> 16;   // round-to-nearest-even
}

static __device__ __forceinline__ void load8(const float* __restrict__ p, float* v) {
    float4 t0 = *reinterpret_cast<const float4*>(p);
    float4 t1 = *reinterpret_cast<const float4*>(p + 4);
    v[0] = t0.x; v[1] = t0.y; v[2] = t0.z; v[3] = t0.w;
    v[4] = t1.x; v[5] = t1.y; v[6] = t1.z; v[7] = t1.w;
}

static __device__ __forceinline__ void split8(const float* v, s16x8& hi, s16x8& lo) {
#pragma unroll
    for (int j = 0; j < 8; ++j) {
        unsigned h = bf16_rne(v[j]);
        float hf = __builtin_bit_cast(float, h << 16);
        unsigned l = bf16_rne(v[j] - hf);
        hi[j] = (short)h;
        lo[j] = (short)l;
    }
}

__global__ __launch_bounds__(THREADS) void rbf_stream(
    const float* __restrict__ x,
    const float* __restrict__ centers,
    const float* __restrict__ gamma,
    float* __restrict__ out)
{
    const int tid  = threadIdx.x;
    const int wid  = tid >> 6;
    const int lane = tid & 63;
    const int wm   = wid >> 1;        // wave M index 0..1 (32 rows each)
    const int wn   = wid & 1;         // wave N index 0..1 (64 cols each)
    const int l16  = lane & 15;
    const int kq   = lane >> 4;       // 0..3

    // ---- XCD-slab block mapping ----
    const int bid = blockIdx.x;       // 0..511
    const int xcd = bid & (NXCD - 1); // dispatch round-robins XCDs
    const int rlo = bid >> 3;         // 0..63 within XCD
    const int cb  = rlo & 15;         // col block 0..15
    const int sb  = rlo >> 4;         // row slot 0..3
    const int c0  = cb * BN;
    // row-block at iter k: xcd*16 + k*4 + sb  (per-XCD 2MB contiguous window
    // of 4 consecutive row-blocks x all 16 col stripes at each k)

    const float kg = -gamma[0] * 1.4426950408889634f;  // -g*log2(e)
    const float m2 = -2.0f * kg;

    // ---- prologue (once per block): center fragments + kg*||c||^2 ----
    s16x8 b_hi[4], b_lo[4];
    float kgcnq[4][4];                // [n][j]: kg*||c_{n*16+kq*4+j}||^2
#pragma unroll
    for (int n = 0; n < 4; ++n) {
        float v[8];
        load8(centers + (size_t)(c0 + wn * 64 + n * 16 + l16) * DIM + kq * 8, v);
        split8(v, b_hi[n], b_lo[n]);
        float pn = 0.f;
#pragma unroll
        for (int j = 0; j < 8; ++j) pn = fmaf(v[j], v[j], pn);
        pn += __shfl_xor(pn, 16);
        pn += __shfl_xor(pn, 32);     // lane now holds ||c_{l16}||^2 of tile n
#pragma unroll
        for (int j = 0; j < 4; ++j)
            kgcnq[n][j] = kg * __shfl(pn, kq * 4 + j);
    }

    // ---- row-tile loop, software-pipelined x loads ----
    float xf[2][2][8];                // [buf][m][elem]
    {
        const int r0 = (xcd * 16 + sb) * BM;           // k = 0
#pragma unroll
        for (int m = 0; m < 2; ++m)
            load8(x + (size_t)(r0 + wm * 32 + m * 16 + l16) * DIM + kq * 8, xf[0][m]);
    }

#pragma unroll
    for (int k = 0; k < ITERS; ++k) {
        const int cur = k & 1;
        const int r0  = (xcd * 16 + k * 4 + sb) * BM;

        if (k + 1 < ITERS) {          // prefetch next tile into other buffer
            const int r1 = (xcd * 16 + (k + 1) * 4 + sb) * BM;
#pragma unroll
            for (int m = 0; m < 2; ++m)
                load8(x + (size_t)(r1 + wm * 32 + m * 16 + l16) * DIM + kq * 8,
                      xf[cur ^ 1][m]);
        }

        // convert + per-row norms (wave-local, no LDS)
        s16x8 a_hi[2], a_lo[2];
        float kgxn[2];
#pragma unroll
        for (int m = 0; m < 2; ++m) {
            split8(xf[cur][m], a_hi[m], a_lo[m]);
            float pn = 0.f;
#pragma unroll
            for (int j = 0; j < 8; ++j) pn = fmaf(xf[cur][m][j], xf[cur][m][j], pn);
            pn += __shfl_xor(pn, 16);
            pn += __shfl_xor(pn, 32); // full norm of row l16 (tile m)
            kgxn[m] = kg * pn;
        }

        // MFMA (swapped: D = c . x^T) + epilogue with dwordx4 stores
#pragma unroll
        for (int m = 0; m < 2; ++m) {
#pragma unroll
            for (int n = 0; n < 4; ++n) {
                f32x4 acc = {0.f, 0.f, 0.f, 0.f};
                acc = __builtin_amdgcn_mfma_f32_16x16x32_bf16(b_lo[n], a_hi[m], acc, 0, 0, 0);
                acc = __builtin_amdgcn_mfma_f32_16x16x32_bf16(b_hi[n], a_lo[m], acc, 0, 0, 0);
                acc = __builtin_amdgcn_mfma_f32_16x16x32_bf16(b_hi[n], a_hi[m], acc, 0, 0, 0);

                float4 o;
                o.x = __builtin_amdgcn_exp2f(fmaf(m2, acc[0], kgxn[m] + kgcnq[n][0]));
                o.y = __builtin_amdgcn_exp2f(fmaf(m2, acc[1], kgxn[m] + kgcnq[n][1]));
                o.z = __builtin_amdgcn_exp2f(fmaf(m2, acc[2], kgxn[m] + kgcnq[n][2]));
                o.w = __builtin_amdgcn_exp2f(fmaf(m2, acc[3], kgxn[m] + kgcnq[n][3]));

                float* op = out + (size_t)(r0 + wm * 32 + m * 16 + l16) * UNITS
                                + (c0 + wn * 64 + n * 16 + kq * 4);
                *reinterpret_cast<float4*>(op) = o;
            }
        }
    }
}

extern "C" void kernel_launch(void* const* d_in, const int* in_sizes, int n_in,
                              void* d_out, int out_size, void* d_ws, size_t ws_size,
                              hipStream_t stream)
{
    const float* x       = (const float*)d_in[0];
    const float* centers = (const float*)d_in[1];
    const float* gamma   = (const float*)d_in[2];
    float* out           = (float*)d_out;

    dim3 grid(512);                   // 1D; mapping done in-kernel
    dim3 block(THREADS);
    rbf_stream<<<grid, block, 0, stream>>>(x, centers, gamma, out);
}